// Round 1
// baseline (10789.091 us; speedup 1.0000x reference)
//
#include <hip/hip_runtime.h>
#include <math.h>

namespace {

constexpr int NCg = 128;   // cells
constexpr int Nc  = 64;    // neurons per cell
constexpr int Dn  = 64;    // feature dim
constexpr int Ag  = 4;     // ports
constexpr int Hm  = 128;   // MLP hidden
constexpr int Tg  = 16;    // timesteps
constexpr int LDP = 68;    // padded LDS row: 16B-aligned rows, bank = (4*row+col)%32

__global__ __launch_bounds__(256, 3) void memgraph_fp32(
    const float* __restrict__ x,      // [B,T,NC,Dn]
    const float* __restrict__ h0,     // [B,NC,Nc,Dn]
    const float* __restrict__ W0,     // [B,NC,Nc,Nc]
    const float* __restrict__ heb0,   // [B,NC,Nc,Nc]
    const float* __restrict__ nid,    // [NC,Nc,Dn]
    const float* __restrict__ w1,     // [Hm,Dn]
    const float* __restrict__ b1,     // [Hm]
    const float* __restrict__ w2,     // [Dn,Hm]
    const float* __restrict__ b2,     // [Dn]
    const float* __restrict__ injw,   // [NC,A*Dn,Dn]
    const float* __restrict__ injb,   // [NC,A*Dn]
    const float* __restrict__ wdl,    // [NC,Nc]
    const float* __restrict__ dgl,    // [NC,Nc]
    const float* __restrict__ hdl,    // [NC,Nc]
    const int*  __restrict__ iport,   // [NC,A]
    const int*  __restrict__ oport,   // [NC,A]
    float* __restrict__ out)          // [B,T,NC*Dn]
{
    __shared__ float h_s[Nc][LDP];    // state h (becomes h_in after scatter)
    __shared__ float heb_s[Nc][LDP];  // hebbian fast weights
    __shared__ float s1_s[Nc][LDP];   // m1 scratch

    const int bc  = blockIdx.x;
    const int b   = bc >> 7;
    const int c   = bc & (NCg - 1);
    const int tid = threadIdx.x;
    const int i   = tid >> 2;       // my neuron row (0..63)
    const int q   = tid & 3;        // quarter within row
    const int d0  = q * 16;         // my d-chunk start

    const size_t cellBase = (size_t)(b * NCg + c);

    // ---- load state into LDS ----
    const float* h0p  = h0   + cellBase * (Nc * Dn);
    const float* hb0p = heb0 + cellBase * (Nc * Nc);
    for (int u = tid; u < Nc * Dn; u += 256) {
        h_s[u >> 6][u & 63]   = h0p[u];
        heb_s[u >> 6][u & 63] = hb0p[u];
    }

    // ---- per-row gates (row i) ----
    const float gi    = 0.5f / (1.0f + expf(-dgl[c * Nc + i]));
    const float hgi   = 0.5f / (1.0f + expf(-hdl[c * Nc + i]));
    const float wdeci = 1.0f - 0.5f / (1.0f + expf(-wdl[c * Nc + i]));
    float wpow = 1.0f;  // (1-wg_i)^t, W used BEFORE decay at each step

    const float4* w0row  = (const float4*)(W0 + (cellBase * Nc + i) * Nc);
    const float*  nidrow = nid + (c * Nc + i) * Dn + d0;
    const int pin = iport[c * Ag + (tid >> 6)];  // wave-uniform port for my inj row
    const int o0 = oport[c * Ag + 0], o1 = oport[c * Ag + 1];
    const int o2 = oport[c * Ag + 2], o3 = oport[c * Ag + 3];
    const float4* injrow  = (const float4*)(injw + ((size_t)c * (Ag * Dn) + tid) * Dn);
    const float   injbias = injb[c * (Ag * Dn) + tid];

    __syncthreads();

    #pragma unroll 1
    for (int t = 0; t < Tg; ++t) {
        // ======== phase 1: injection  inj[p] = b + x_t[c] . injw[c][p] ========
        const float4* xt = (const float4*)(x + (((size_t)(b * Tg + t)) * NCg + c) * Dn);
        float inj = injbias;
        #pragma unroll
        for (int k = 0; k < 16; ++k) {
            float4 w = injrow[k], xv = xt[k];
            inj += w.x * xv.x + w.y * xv.y + w.z * xv.z + w.w * xv.w;
        }
        // scatter-add onto input port (duplicates accumulate, like .at[].add)
        atomicAdd(&h_s[pin][tid & 63], inj);
        __syncthreads();   // h_in ready

        // ======== phase 2: m1 = (W0*wpow + heb) @ h_in  -> s1 ========
        {
            float acc[16];
            #pragma unroll
            for (int k = 0; k < 16; ++k) acc[k] = 0.0f;
            #pragma unroll 1
            for (int j4 = 0; j4 < 16; ++j4) {
                float4 wv = w0row[j4];
                float4 hb = ((const float4*)&heb_s[i][0])[j4];
                float wes[4];
                wes[0] = wv.x * wpow + hb.x;
                wes[1] = wv.y * wpow + hb.y;
                wes[2] = wv.z * wpow + hb.z;
                wes[3] = wv.w * wpow + hb.w;
                #pragma unroll
                for (int s = 0; s < 4; ++s) {
                    const float4* hj = (const float4*)&h_s[4 * j4 + s][d0];
                    float4 a0 = hj[0], a1 = hj[1], a2 = hj[2], a3 = hj[3];
                    const float w = wes[s];
                    acc[0]  += w * a0.x; acc[1]  += w * a0.y; acc[2]  += w * a0.z; acc[3]  += w * a0.w;
                    acc[4]  += w * a1.x; acc[5]  += w * a1.y; acc[6]  += w * a1.z; acc[7]  += w * a1.w;
                    acc[8]  += w * a2.x; acc[9]  += w * a2.y; acc[10] += w * a2.z; acc[11] += w * a2.w;
                    acc[12] += w * a3.x; acc[13] += w * a3.y; acc[14] += w * a3.z; acc[15] += w * a3.w;
                }
            }
            float4* s1w = (float4*)&s1_s[i][d0];
            s1w[0] = make_float4(acc[0],  acc[1],  acc[2],  acc[3]);
            s1w[1] = make_float4(acc[4],  acc[5],  acc[6],  acc[7]);
            s1w[2] = make_float4(acc[8],  acc[9],  acc[10], acc[11]);
            s1w[3] = make_float4(acc[12], acc[13], acc[14], acc[15]);
        }
        __syncthreads();   // s1 ready; all h readers of phase 2 done

        // ======== phase 3a: hidden[q*32+u] = tanh(b1 + m1[i,:] . w1[hh,:]) ========
        float hid[32];
        #pragma unroll
        for (int u = 0; u < 32; ++u) hid[u] = b1[q * 32 + u];
        #pragma unroll 1
        for (int kb = 0; kb < 4; ++kb) {
            const float4* s1r = (const float4*)&s1_s[i][kb * 16];
            float4 ma = s1r[0], mb = s1r[1], mc = s1r[2], md = s1r[3];
            #pragma unroll
            for (int u = 0; u < 32; ++u) {
                const float4* w1r = (const float4*)(w1 + (q * 32 + u) * Dn + kb * 16);
                float4 wa = w1r[0], wb = w1r[1], wc = w1r[2], wd = w1r[3];
                hid[u] += ma.x * wa.x + ma.y * wa.y + ma.z * wa.z + ma.w * wa.w
                        + mb.x * wb.x + mb.y * wb.y + mb.z * wb.z + mb.w * wb.w
                        + mc.x * wc.x + mc.y * wc.y + mc.z * wc.z + mc.w * wc.w
                        + md.x * wd.x + md.y * wd.y + md.z * wd.z + md.w * wd.w;
            }
        }
        #pragma unroll
        for (int u = 0; u < 32; ++u) hid[u] = tanhf(hid[u]);

        // ======== phase 3b: m2[d] = sum_hh hid[hh]*w2[d,hh]; reduce over 4 lanes ====
        float m2v[16];
        #pragma unroll 1
        for (int half = 0; half < 2; ++half) {
            float pm[32];
            #pragma unroll
            for (int dd = 0; dd < 32; ++dd) {
                const int d = half * 32 + dd;
                const float4* w2r = (const float4*)(w2 + d * Hm + q * 32);
                float a = 0.0f;
                #pragma unroll
                for (int u8 = 0; u8 < 8; ++u8) {
                    float4 wv = w2r[u8];
                    a += hid[u8 * 4 + 0] * wv.x + hid[u8 * 4 + 1] * wv.y
                       + hid[u8 * 4 + 2] * wv.z + hid[u8 * 4 + 3] * wv.w;
                }
                pm[dd] = a;
            }
            // reduce partial m2 across the 4 lanes sharing row i (adjacent lanes)
            #pragma unroll
            for (int dd = 0; dd < 32; ++dd) {
                pm[dd] += __shfl_xor(pm[dd], 1);
                pm[dd] += __shfl_xor(pm[dd], 2);
            }
            if ((q >> 1) == half) {
                #pragma unroll
                for (int k = 0; k < 16; ++k)
                    m2v[k] = (q & 1) ? pm[16 + k] : pm[k];
            }
        }

        // ======== phase 5: h_new = (1-g)*h_in + g*tanh(m2 + b2 + neuron_id) ========
        // safe without extra barrier: only this thread touches h_s[i][d0..d0+15] here
        #pragma unroll
        for (int k = 0; k < 16; ++k) {
            float hin = h_s[i][d0 + k];
            float tv  = tanhf(m2v[k] + b2[d0 + k] + nidrow[k]);
            h_s[i][d0 + k] = (1.0f - gi) * hin + gi * tv;
        }
        __syncthreads();   // h_new visible to all

        // ======== phase 6: heb = ((1-hg)*heb + hg*(h h^T)/64) * (1-eye) ========
        {
            float accj[16];
            #pragma unroll
            for (int s = 0; s < 16; ++s) accj[s] = 0.0f;
            const int jc = q * 16;
            #pragma unroll 2
            for (int dq = 0; dq < 16; ++dq) {
                float4 hi = *(const float4*)&h_s[i][dq * 4];
                #pragma unroll
                for (int s = 0; s < 16; ++s) {
                    float4 hj = *(const float4*)&h_s[jc + s][dq * 4];
                    accj[s] += hi.x * hj.x + hi.y * hj.y + hi.z * hj.z + hi.w * hj.w;
                }
            }
            #pragma unroll
            for (int s = 0; s < 16; ++s) {
                const int j = jc + s;
                float nw = (1.0f - hgi) * heb_s[i][j] + hgi * (accj[s] * (1.0f / 64.0f));
                heb_s[i][j] = (j == i) ? 0.0f : nw;
            }
        }

        // ======== phase 7: readout  ro[d] = 0.125 * sum_a h[oport_a][d] ========
        if (tid < 64) {
            const int d = tid;
            float ro = 0.125f * (h_s[o0][d] + h_s[o1][d] + h_s[o2][d] + h_s[o3][d]);
            out[(((size_t)(b * Tg + t)) * NCg + c) * Dn + d] = ro;
        }

        wpow *= wdeci;
        __syncthreads();   // protect h (next scatter) and heb (next phase 2)
    }
}

} // namespace

extern "C" void kernel_launch(void* const* d_in, const int* in_sizes, int n_in,
                              void* d_out, int out_size, void* d_ws, size_t ws_size,
                              hipStream_t stream) {
    (void)in_sizes; (void)n_in; (void)out_size; (void)d_ws; (void)ws_size;
    const float* x    = (const float*)d_in[0];
    const float* h0   = (const float*)d_in[1];
    const float* W0   = (const float*)d_in[2];
    const float* heb0 = (const float*)d_in[3];
    const float* nid  = (const float*)d_in[4];
    const float* w1   = (const float*)d_in[5];
    const float* b1   = (const float*)d_in[6];
    const float* w2   = (const float*)d_in[7];
    const float* b2   = (const float*)d_in[8];
    const float* injw = (const float*)d_in[9];
    const float* injb = (const float*)d_in[10];
    const float* wdl  = (const float*)d_in[11];
    const float* dgl  = (const float*)d_in[12];
    const float* hdl  = (const float*)d_in[13];
    const int*   ip   = (const int*)d_in[14];
    const int*   op   = (const int*)d_in[15];
    float* out = (float*)d_out;

    memgraph_fp32<<<dim3(8 * 128), dim3(256), 0, stream>>>(
        x, h0, W0, heb0, nid, w1, b1, w2, b2, injw, injb,
        wdl, dgl, hdl, ip, op, out);
}

// Round 2
// 7952.927 us; speedup vs baseline: 1.3566x; 1.3566x over previous
//
#include <hip/hip_runtime.h>
#include <math.h>

namespace {

constexpr int NCg = 128;   // cells
constexpr int Nc  = 64;    // neurons per cell
constexpr int Dn  = 64;    // feature dim
constexpr int Ag  = 4;     // ports
constexpr int Hm  = 128;   // MLP hidden
constexpr int Tg  = 16;    // timesteps
constexpr int LDP = 68;    // padded LDS row

__global__ __launch_bounds__(256, 3) void memgraph_fp32(
    const float* __restrict__ x,      // [B,T,NC,Dn]
    const float* __restrict__ h0,     // [B,NC,Nc,Dn]
    const float* __restrict__ W0,     // [B,NC,Nc,Nc]
    const float* __restrict__ heb0,   // [B,NC,Nc,Nc]
    const float* __restrict__ nid,    // [NC,Nc,Dn]
    const float* __restrict__ w1,     // [Hm,Dn]
    const float* __restrict__ b1,     // [Hm]
    const float* __restrict__ w2,     // [Dn,Hm]
    const float* __restrict__ b2,     // [Dn]
    const float* __restrict__ injw,   // [NC,A*Dn,Dn]
    const float* __restrict__ injb,   // [NC,A*Dn]
    const float* __restrict__ wdl,    // [NC,Nc]
    const float* __restrict__ dgl,    // [NC,Nc]
    const float* __restrict__ hdl,    // [NC,Nc]
    const int*  __restrict__ iport,   // [NC,A]
    const int*  __restrict__ oport,   // [NC,A]
    float* __restrict__ out)          // [B,T,NC*Dn]
{
    __shared__ float h_s[Nc][LDP];    // state h (becomes h_in after scatter)
    __shared__ float heb_s[Nc][LDP];  // hebbian fast weights
    __shared__ float s1_s[Nc][LDP];   // m1 scratch

    const int bc  = blockIdx.x;
    const int b   = bc >> 7;
    const int c   = bc & (NCg - 1);
    const int tid = threadIdx.x;
    const int i   = tid >> 2;       // my neuron row (0..63)
    const int q   = tid & 3;        // quarter within row
    const int d0  = q * 16;        // my d-chunk start

    const size_t cellBase = (size_t)(b * NCg + c);

    // ---- load state into LDS ----
    const float* h0p  = h0   + cellBase * (Nc * Dn);
    const float* hb0p = heb0 + cellBase * (Nc * Nc);
    for (int u = tid; u < Nc * Dn; u += 256) {
        h_s[u >> 6][u & 63]   = h0p[u];
        heb_s[u >> 6][u & 63] = hb0p[u];
    }

    // ---- per-row gates (row i) ----
    const float gi    = 0.5f / (1.0f + expf(-dgl[c * Nc + i]));
    const float hgi   = 0.5f / (1.0f + expf(-hdl[c * Nc + i]));
    const float wdeci = 1.0f - 0.5f / (1.0f + expf(-wdl[c * Nc + i]));
    float wpow = 1.0f;  // (1-wg_i)^t, W used BEFORE decay at each step

    const float4* w0row  = (const float4*)(W0 + (cellBase * Nc + i) * Nc);
    const int pin = iport[c * Ag + (tid >> 6)];  // wave-uniform port for my inj row
    const int o0 = oport[c * Ag + 0], o1 = oport[c * Ag + 1];
    const int o2 = oport[c * Ag + 2], o3 = oport[c * Ag + 3];
    const float4* injrow  = (const float4*)(injw + ((size_t)c * (Ag * Dn) + tid) * Dn);
    const float   injbias = injb[c * (Ag * Dn) + tid];

    // hoist per-step-invariant bias: b2[d] + neuron_id[c,i,d] for my 16 d's
    float nb[16];
    {
        const float* nidrow = nid + (c * Nc + i) * Dn + d0;
        #pragma unroll
        for (int k = 0; k < 16; ++k) nb[k] = b2[d0 + k] + nidrow[k];
    }

    __syncthreads();

    #pragma unroll 1
    for (int t = 0; t < Tg; ++t) {
        // ======== phase 1: injection  inj[p] = b + x_t[c] . injw[c][p] ========
        const float4* xt = (const float4*)(x + (((size_t)(b * Tg + t)) * NCg + c) * Dn);
        float inj = injbias;
        #pragma unroll 4
        for (int k = 0; k < 16; ++k) {
            float4 w = injrow[k], xv = xt[k];
            inj += w.x * xv.x + w.y * xv.y + w.z * xv.z + w.w * xv.w;
        }
        // scatter-add onto input port (duplicates accumulate, like .at[].add)
        atomicAdd(&h_s[pin][tid & 63], inj);
        __syncthreads();   // h_in ready

        // ======== phase 2: m1 = (W0*wpow + heb) @ h_in  -> s1 ========
        {
            float acc[16];
            #pragma unroll
            for (int k = 0; k < 16; ++k) acc[k] = 0.0f;
            #pragma unroll 1
            for (int j4 = 0; j4 < 16; ++j4) {
                float4 wv = w0row[j4];
                float4 hb = ((const float4*)&heb_s[i][0])[j4];
                float wes[4];
                wes[0] = wv.x * wpow + hb.x;
                wes[1] = wv.y * wpow + hb.y;
                wes[2] = wv.z * wpow + hb.z;
                wes[3] = wv.w * wpow + hb.w;
                #pragma unroll
                for (int s = 0; s < 4; ++s) {
                    const float4* hj = (const float4*)&h_s[4 * j4 + s][d0];
                    float4 a0 = hj[0], a1 = hj[1], a2 = hj[2], a3 = hj[3];
                    const float w = wes[s];
                    acc[0]  += w * a0.x; acc[1]  += w * a0.y; acc[2]  += w * a0.z; acc[3]  += w * a0.w;
                    acc[4]  += w * a1.x; acc[5]  += w * a1.y; acc[6]  += w * a1.z; acc[7]  += w * a1.w;
                    acc[8]  += w * a2.x; acc[9]  += w * a2.y; acc[10] += w * a2.z; acc[11] += w * a2.w;
                    acc[12] += w * a3.x; acc[13] += w * a3.y; acc[14] += w * a3.z; acc[15] += w * a3.w;
                }
            }
            float4* s1w = (float4*)&s1_s[i][d0];
            s1w[0] = make_float4(acc[0],  acc[1],  acc[2],  acc[3]);
            s1w[1] = make_float4(acc[4],  acc[5],  acc[6],  acc[7]);
            s1w[2] = make_float4(acc[8],  acc[9],  acc[10], acc[11]);
            s1w[3] = make_float4(acc[12], acc[13], acc[14], acc[15]);
        }
        __syncthreads();   // s1 ready; all h readers of phase 2 done

        // ======== phase 3a: hidden[q*32+u] = tanh(b1 + m1[i,:] . w1[hh,:]) ========
        float hid[32];
        {
            const float4* b1v = (const float4*)(b1 + q * 32);
            #pragma unroll
            for (int u4 = 0; u4 < 8; ++u4) {
                float4 bv = b1v[u4];
                hid[4*u4+0] = bv.x; hid[4*u4+1] = bv.y;
                hid[4*u4+2] = bv.z; hid[4*u4+3] = bv.w;
            }
        }
        #pragma unroll 1
        for (int kb = 0; kb < 4; ++kb) {
            const float4* s1r = (const float4*)&s1_s[i][kb * 16];
            float4 ma = s1r[0], mb = s1r[1], mc = s1r[2], md = s1r[3];
            #pragma unroll 4
            for (int u = 0; u < 32; ++u) {
                const float4* w1r = (const float4*)(w1 + (q * 32 + u) * Dn + kb * 16);
                float4 wa = w1r[0], wb = w1r[1], wc = w1r[2], wd = w1r[3];
                hid[u] += ma.x * wa.x + ma.y * wa.y + ma.z * wa.z + ma.w * wa.w
                        + mb.x * wb.x + mb.y * wb.y + mb.z * wb.z + mb.w * wb.w
                        + mc.x * wc.x + mc.y * wc.y + mc.z * wc.z + mc.w * wc.w
                        + md.x * wd.x + md.y * wd.y + md.z * wd.z + md.w * wd.w;
            }
        }
        #pragma unroll 4
        for (int u = 0; u < 32; ++u) hid[u] = tanhf(hid[u]);

        // ======== phase 3b: m2[d] partials in quarter-chunks of 16 ========
        float m2v[16];
        #pragma unroll 1
        for (int p = 0; p < 4; ++p) {
            float pm[16];
            #pragma unroll 2
            for (int k = 0; k < 16; ++k) {
                const float4* w2r = (const float4*)(w2 + (16 * p + k) * Hm + q * 32);
                float a = 0.0f;
                #pragma unroll
                for (int u8 = 0; u8 < 8; ++u8) {
                    float4 wv = w2r[u8];
                    a += hid[u8 * 4 + 0] * wv.x + hid[u8 * 4 + 1] * wv.y
                       + hid[u8 * 4 + 2] * wv.z + hid[u8 * 4 + 3] * wv.w;
                }
                pm[k] = a;
            }
            // reduce partial m2 across the 4 lanes sharing row i (adjacent lanes)
            #pragma unroll
            for (int k = 0; k < 16; ++k) {
                pm[k] += __shfl_xor(pm[k], 1);
                pm[k] += __shfl_xor(pm[k], 2);
            }
            if (q == p) {
                #pragma unroll
                for (int k = 0; k < 16; ++k) m2v[k] = pm[k];
            }
        }

        // ======== phase 5: h_new = (1-g)*h_in + g*tanh(m2 + b2 + neuron_id) ========
        // safe without extra barrier: only this thread touches h_s[i][d0..d0+15] here
        #pragma unroll 4
        for (int k = 0; k < 16; ++k) {
            float hin = h_s[i][d0 + k];
            float tv  = tanhf(m2v[k] + nb[k]);
            h_s[i][d0 + k] = (1.0f - gi) * hin + gi * tv;
        }
        __syncthreads();   // h_new visible to all

        // ======== phase 6: heb = ((1-hg)*heb + hg*(h h^T)/64) * (1-eye) ========
        {
            float accj[16];
            #pragma unroll
            for (int s = 0; s < 16; ++s) accj[s] = 0.0f;
            const int jc = q * 16;
            #pragma unroll 2
            for (int dq = 0; dq < 16; ++dq) {
                float4 hi = *(const float4*)&h_s[i][dq * 4];
                #pragma unroll
                for (int s = 0; s < 16; ++s) {
                    float4 hj = *(const float4*)&h_s[jc + s][dq * 4];
                    accj[s] += hi.x * hj.x + hi.y * hj.y + hi.z * hj.z + hi.w * hj.w;
                }
            }
            #pragma unroll
            for (int s = 0; s < 16; ++s) {
                const int j = jc + s;
                float nw = (1.0f - hgi) * heb_s[i][j] + hgi * (accj[s] * (1.0f / 64.0f));
                heb_s[i][j] = (j == i) ? 0.0f : nw;
            }
        }

        // ======== phase 7: readout  ro[d] = 0.125 * sum_a h[oport_a][d] ========
        if (tid < 64) {
            const int d = tid;
            float ro = 0.125f * (h_s[o0][d] + h_s[o1][d] + h_s[o2][d] + h_s[o3][d]);
            out[(((size_t)(b * Tg + t)) * NCg + c) * Dn + d] = ro;
        }

        wpow *= wdeci;
        __syncthreads();   // protect h (next scatter) and heb (next phase 2)
    }
}

} // namespace

extern "C" void kernel_launch(void* const* d_in, const int* in_sizes, int n_in,
                              void* d_out, int out_size, void* d_ws, size_t ws_size,
                              hipStream_t stream) {
    (void)in_sizes; (void)n_in; (void)out_size; (void)d_ws; (void)ws_size;
    const float* x    = (const float*)d_in[0];
    const float* h0   = (const float*)d_in[1];
    const float* W0   = (const float*)d_in[2];
    const float* heb0 = (const float*)d_in[3];
    const float* nid  = (const float*)d_in[4];
    const float* w1   = (const float*)d_in[5];
    const float* b1   = (const float*)d_in[6];
    const float* w2   = (const float*)d_in[7];
    const float* b2   = (const float*)d_in[8];
    const float* injw = (const float*)d_in[9];
    const float* injb = (const float*)d_in[10];
    const float* wdl  = (const float*)d_in[11];
    const float* dgl  = (const float*)d_in[12];
    const float* hdl  = (const float*)d_in[13];
    const int*   ip   = (const int*)d_in[14];
    const int*   op   = (const int*)d_in[15];
    float* out = (float*)d_out;

    memgraph_fp32<<<dim3(8 * 128), dim3(256), 0, stream>>>(
        x, h0, W0, heb0, nid, w1, b1, w2, b2, injw, injb,
        wdl, dgl, hdl, ip, op, out);
}

// Round 3
// 854.060 us; speedup vs baseline: 12.6327x; 9.3119x over previous
//
#include <hip/hip_runtime.h>
#include <math.h>

namespace {

typedef __attribute__((ext_vector_type(8))) short bf16x8;
typedef __attribute__((ext_vector_type(4))) float f32x4;

constexpr int NCg = 128;

// ---- helpers ----
__device__ inline short bfr(float f) {            // fp32 -> bf16 RNE
    unsigned u = __float_as_uint(f);
    unsigned r = (u + 0x7fffu + ((u >> 16) & 1u)) >> 16;
    return (short)r;
}
__device__ inline unsigned pack2(float a, float b) {
    return (unsigned)(unsigned short)bfr(a) | ((unsigned)(unsigned short)bfr(b) << 16);
}
__device__ inline float tanh_f(float x) {         // 1 - 2/(e^{2x}+1)
    float t = __builtin_amdgcn_exp2f(x * 2.8853900817779268f);
    return 1.0f - 2.0f * __builtin_amdgcn_rcpf(t + 1.0f);
}
__device__ inline float sig05(float x) { return 0.5f / (1.0f + expf(-x)); }

// LDS bf16 tiles, K-contiguous, XOR-swizzled: byte ^= (row&7)<<4
__device__ inline bf16x8 ld64(const short* base, int row, int kbyte) {   // pitch 64 bf16 = 128B
    int byte = (row << 7) + kbyte; byte ^= (row & 7) << 4;
    return *(const bf16x8*)((const char*)base + byte);
}
__device__ inline bf16x8 ld128(const short* base, int row, int kbyte) {  // pitch 128 bf16 = 256B
    int byte = (row << 8) + kbyte; byte ^= (row & 7) << 4;
    return *(const bf16x8*)((const char*)base + byte);
}
__device__ inline void st16_64(short* base, int row, int col, short v) {
    int byte = (row << 7) + (col << 1); byte ^= (row & 7) << 4;
    *(short*)((char*)base + byte) = v;
}
__device__ inline void st32_64(short* base, int row, int col, unsigned v) { // col even
    int byte = (row << 7) + (col << 1); byte ^= (row & 7) << 4;
    *(unsigned*)((char*)base + byte) = v;
}
__device__ inline void st32_128(short* base, int row, int col, unsigned v) { // col even
    int byte = (row << 8) + (col << 1); byte ^= (row & 7) << 4;
    *(unsigned*)((char*)base + byte) = v;
}
__device__ inline bf16x8 ldg_bf(const float* p) {  // 8 consecutive fp32 -> bf16x8
    float4 a = *(const float4*)p, b = *(const float4*)(p + 4);
    bf16x8 r;
    r[0]=bfr(a.x); r[1]=bfr(a.y); r[2]=bfr(a.z); r[3]=bfr(a.w);
    r[4]=bfr(b.x); r[5]=bfr(b.y); r[6]=bfr(b.z); r[7]=bfr(b.w);
    return r;
}
#define MFMA(a,b,c) __builtin_amdgcn_mfma_f32_16x16x32_bf16(a, b, c, 0, 0, 0)

__global__ __launch_bounds__(256, 3) void memgraph_mfma(
    const float* __restrict__ x,      const float* __restrict__ h0,
    const float* __restrict__ W0,     const float* __restrict__ heb0,
    const float* __restrict__ nid,    const float* __restrict__ w1,
    const float* __restrict__ b1,     const float* __restrict__ w2,
    const float* __restrict__ b2,     const float* __restrict__ injw,
    const float* __restrict__ injb,   const float* __restrict__ wdl,
    const float* __restrict__ dgl,    const float* __restrict__ hdl,
    const int*  __restrict__ iport,   const int*  __restrict__ oport,
    float* __restrict__ out)
{
    __shared__ float h_s[64][65];     // fp32 state (pitch 65: ~2-way banks on col access)
    __shared__ float heb_s[64][65];   // fp32 hebbian
    __shared__ short arena[8192] __attribute__((aligned(16)));  // 16KB bf16 scratch
    __shared__ float xl[16][64] __attribute__((aligned(16)));   // x[t][d] stage

    short* Wf   = arena;              // [64][64] (W+heb) bf16        S0
    short* hinT = arena + 4096;       // [d][j] = h_in^T bf16         S1
    short* m1A  = arena;              // [i][k] m1 bf16               S0 (post-P2)
    short* hidA = arena;              // [i][hh] tanh-hid bf16        S0+S1 (pitch 128)
    short* hnA  = arena;              // [i][d] h_new bf16            S0 (post-P3b)

    const int bc  = blockIdx.x;
    const int b   = bc >> 7;
    const int c   = bc & (NCg - 1);
    const int tid = threadIdx.x;
    const int Wv  = tid >> 6;          // wave id 0..3
    const int l   = tid & 63;
    const int g   = l >> 4;            // 0..3
    const int lm  = l & 15;
    const int rowC = 16 * Wv + 4 * g;  // C-frag row base (+reg r)
    const int kb0  = 16 * g;           // fragment k-byte base

    const size_t cellBase = (size_t)bc;

    // ---- prologue: state load ----
    const float* h0p  = h0   + cellBase * 4096;
    const float* hb0p = heb0 + cellBase * 4096;
    #pragma unroll
    for (int u = 0; u < 16; ++u) {
        int e = tid + 256 * u;
        h_s[e >> 6][e & 63]   = h0p[e];
        heb_s[e >> 6][e & 63] = hb0p[e];
    }
    {   // stage x[t][d] for this (b,c)
        int t0 = tid >> 4, d4 = (tid & 15) << 2;
        *(float4*)&xl[t0][d4] =
            *(const float4*)(x + (((size_t)b * 16 + t0) * NCg + c) * 64 + d4);
    }

    // ---- per-lane constants ----
    float gi4[4], hg4[4], wdec4[4], wpow4[4], nbv[16], b1v8[8];
    #pragma unroll
    for (int r = 0; r < 4; ++r) {
        int i = rowC + r;
        gi4[r]   = sig05(dgl[c * 64 + i]);
        hg4[r]   = sig05(hdl[c * 64 + i]);
        wdec4[r] = 1.0f - sig05(wdl[c * 64 + i]);
        wpow4[r] = 1.0f;
    }
    #pragma unroll
    for (int nt = 0; nt < 4; ++nt)
        #pragma unroll
        for (int r = 0; r < 4; ++r)
            nbv[nt * 4 + r] = b2[lm + 16 * nt] +
                nid[((size_t)c * 64 + rowC + r) * 64 + lm + 16 * nt];
    #pragma unroll
    for (int mt = 0; mt < 2; ++mt)
        #pragma unroll
        for (int r = 0; r < 4; ++r)
            b1v8[mt * 4 + r] = b1[32 * Wv + 16 * mt + 4 * g + r];

    const int dn  = tid & 63;
    const int pin = iport[c * 4 + Wv];          // wave Wv handles port Wv
    int op4[4];
    #pragma unroll
    for (int a = 0; a < 4; ++a) op4[a] = oport[c * 4 + a];
    const float* injrow  = injw + ((size_t)c * 256 + tid) * 64;
    const float  injbias = injb[c * 256 + tid];
    const float* w0lane  = W0 + cellBase * 4096 + (size_t)rowC * 64 + lm;

    __syncthreads();

    // ---- prologue: build hinT = h^T and Wf = W0 + heb ----
    {
        int d = tid >> 2, q = tid & 3;
        #pragma unroll
        for (int k = 0; k < 16; k += 2) {
            int col = 16 * q + k;
            st32_64(hinT, d, col, pack2(h_s[col][d], h_s[col + 1][d]));
        }
        const float* wr = W0 + cellBase * 4096 + (size_t)d * 64 + 16 * q;
        #pragma unroll
        for (int k = 0; k < 16; k += 2) {
            float a0 = wr[k]     + heb_s[d][16 * q + k];
            float a1 = wr[k + 1] + heb_s[d][16 * q + k + 1];
            st32_64(Wf, d, 16 * q + k, pack2(a0, a1));
        }
    }
    __syncthreads();

    const f32x4 zf = {0.f, 0.f, 0.f, 0.f};

    #pragma unroll 1
    for (int t = 0; t < 16; ++t) {
        int go = 0; asm volatile("" : "+v"(go));   // block LICM of t-invariant global loads

        // ==== P1a: injection + scatter ====
        float inj = injbias;
        #pragma unroll 4
        for (int k = 0; k < 16; ++k) {
            float4 wv = *(const float4*)(injrow + 4 * k + go);
            float4 xv = *(const float4*)&xl[t][4 * k];
            inj += wv.x * xv.x + wv.y * xv.y + wv.z * xv.z + wv.w * xv.w;
        }
        atomicAdd(&h_s[pin][dn], inj);
        __syncthreads();                                           // B1
        // ==== P1b: refresh scattered columns of hinT ====
        st16_64(hinT, dn, pin, bfr(h_s[pin][dn]));                 // dup ports: benign same-value
        __syncthreads();                                           // B2

        // ==== P2: m1 = (wpow*W0+heb) @ h_in ====
        f32x4 acc2[4] = {zf, zf, zf, zf};
        {
            bf16x8 a0 = ld64(Wf, 16 * Wv + lm, kb0);
            bf16x8 a1 = ld64(Wf, 16 * Wv + lm, kb0 + 64);
            #pragma unroll
            for (int nt = 0; nt < 4; ++nt) {
                bf16x8 bb0 = ld64(hinT, lm + 16 * nt, kb0);
                bf16x8 bb1 = ld64(hinT, lm + 16 * nt, kb0 + 64);
                acc2[nt] = MFMA(a0, bb0, acc2[nt]);
                acc2[nt] = MFMA(a1, bb1, acc2[nt]);
            }
        }
        __syncthreads();                                           // B3 (Wf,hinT dead)
        #pragma unroll
        for (int nt = 0; nt < 4; ++nt)
            #pragma unroll
            for (int r = 0; r < 4; ++r)
                st16_64(m1A, rowC + r, lm + 16 * nt, bfr(acc2[nt][r]));
        __syncthreads();                                           // B4

        // ==== P3a: hidT = w1 @ m1^T  (then +b1, tanh) ====
        f32x4 acc3[2][4] = {{zf, zf, zf, zf}, {zf, zf, zf, zf}};
        {
            bf16x8 aw[2][2];
            #pragma unroll
            for (int mt = 0; mt < 2; ++mt)
                #pragma unroll
                for (int kt = 0; kt < 2; ++kt)
                    aw[mt][kt] = ldg_bf(w1 + (32 * Wv + 16 * mt + lm) * 64 + 8 * g + 32 * kt + go);
            #pragma unroll
            for (int kt = 0; kt < 2; ++kt)
                #pragma unroll
                for (int nt = 0; nt < 4; ++nt) {
                    bf16x8 bb = ld64(m1A, lm + 16 * nt, kb0 + 64 * kt);
                    acc3[0][nt] = MFMA(aw[0][kt], bb, acc3[0][nt]);
                    acc3[1][nt] = MFMA(aw[1][kt], bb, acc3[1][nt]);
                }
        }
        __syncthreads();                                           // B5 (m1A dead)
        #pragma unroll
        for (int mt = 0; mt < 2; ++mt)
            #pragma unroll
            for (int nt = 0; nt < 4; ++nt)
                #pragma unroll
                for (int rp = 0; rp < 4; rp += 2) {
                    float v0 = tanh_f(acc3[mt][nt][rp]     + b1v8[mt * 4 + rp]);
                    float v1 = tanh_f(acc3[mt][nt][rp + 1] + b1v8[mt * 4 + rp + 1]);
                    st32_128(hidA, lm + 16 * nt, 32 * Wv + 16 * mt + 4 * g + rp, pack2(v0, v1));
                }
        __syncthreads();                                           // B6

        // ==== P3b: m2 = hid @ w2^T ====
        f32x4 accB[4] = {zf, zf, zf, zf};
        {
            bf16x8 ah[4];
            #pragma unroll
            for (int kt = 0; kt < 4; ++kt)
                ah[kt] = ld128(hidA, 16 * Wv + lm, kb0 + 64 * kt);
            #pragma unroll
            for (int kt = 0; kt < 4; ++kt)
                #pragma unroll
                for (int nt = 0; nt < 4; ++nt) {
                    bf16x8 bb = ldg_bf(w2 + (lm + 16 * nt) * 128 + 8 * g + 32 * kt + go);
                    accB[nt] = MFMA(ah[kt], bb, accB[nt]);
                }
        }
        __syncthreads();                                           // B7 (hidA dead)

        // ==== P5: gated state update; write h_s, hnA, hinT(next) ====
        #pragma unroll
        for (int nt = 0; nt < 4; ++nt) {
            int d = lm + 16 * nt;
            float hv[4];
            #pragma unroll
            for (int r = 0; r < 4; ++r) {
                int i = rowC + r;
                float hin = h_s[i][d];
                float tv  = tanh_f(accB[nt][r] + nbv[nt * 4 + r]);
                hv[r] = (1.0f - gi4[r]) * hin + gi4[r] * tv;
                h_s[i][d] = hv[r];
                st16_64(hnA, i, d, bfr(hv[r]));
            }
            st32_64(hinT, d, rowC,     pack2(hv[0], hv[1]));
            st32_64(hinT, d, rowC + 2, pack2(hv[2], hv[3]));
        }
        __syncthreads();                                           // B8

        // ==== P6: hebbian outer product + fused Wf(next) + readout ====
        f32x4 acc6[4] = {zf, zf, zf, zf};
        {
            bf16x8 ha0 = ld64(hnA, 16 * Wv + lm, kb0);
            bf16x8 ha1 = ld64(hnA, 16 * Wv + lm, kb0 + 64);
            #pragma unroll
            for (int nt = 0; nt < 4; ++nt) {
                bf16x8 bb0 = ld64(hnA, lm + 16 * nt, kb0);
                bf16x8 bb1 = ld64(hnA, lm + 16 * nt, kb0 + 64);
                acc6[nt] = MFMA(ha0, bb0, acc6[nt]);
                acc6[nt] = MFMA(ha1, bb1, acc6[nt]);
            }
        }
        if (tid < 64) {   // readout (h_s stable during P6)
            float ro = 0.125f * (h_s[op4[0]][tid] + h_s[op4[1]][tid] +
                                 h_s[op4[2]][tid] + h_s[op4[3]][tid]);
            out[(((size_t)b * 16 + t) * NCg + c) * 64 + tid] = ro;
        }
        float wfv[4][4];
        #pragma unroll
        for (int r = 0; r < 4; ++r) wpow4[r] *= wdec4[r];
        #pragma unroll
        for (int nt = 0; nt < 4; ++nt)
            #pragma unroll
            for (int r = 0; r < 4; ++r) {
                int i = rowC + r, j = lm + 16 * nt;
                float old = heb_s[i][j];
                float nv  = (1.0f - hg4[r]) * old + hg4[r] * (acc6[nt][r] * 0.015625f);
                nv = (j == i) ? 0.0f : nv;
                heb_s[i][j] = nv;
                wfv[nt][r] = wpow4[r] * w0lane[r * 64 + nt * 16 + go] + nv;
            }
        __syncthreads();                                           // B9 (hnA dead)
        #pragma unroll
        for (int nt = 0; nt < 4; ++nt)
            #pragma unroll
            for (int r = 0; r < 4; ++r)
                st16_64(Wf, rowC + r, lm + 16 * nt, bfr(wfv[nt][r]));
        __syncthreads();                                           // B10
    }
}

} // namespace

extern "C" void kernel_launch(void* const* d_in, const int* in_sizes, int n_in,
                              void* d_out, int out_size, void* d_ws, size_t ws_size,
                              hipStream_t stream) {
    (void)in_sizes; (void)n_in; (void)out_size; (void)d_ws; (void)ws_size;
    const float* x    = (const float*)d_in[0];
    const float* h0   = (const float*)d_in[1];
    const float* W0   = (const float*)d_in[2];
    const float* heb0 = (const float*)d_in[3];
    const float* nid  = (const float*)d_in[4];
    const float* w1   = (const float*)d_in[5];
    const float* b1   = (const float*)d_in[6];
    const float* w2   = (const float*)d_in[7];
    const float* b2   = (const float*)d_in[8];
    const float* injw = (const float*)d_in[9];
    const float* injb = (const float*)d_in[10];
    const float* wdl  = (const float*)d_in[11];
    const float* dgl  = (const float*)d_in[12];
    const float* hdl  = (const float*)d_in[13];
    const int*   ip   = (const int*)d_in[14];
    const int*   op   = (const int*)d_in[15];
    float* out = (float*)d_out;

    memgraph_mfma<<<dim3(8 * NCg), dim3(256), 0, stream>>>(
        x, h0, W0, heb0, nid, w1, b1, w2, b2, injw, injb,
        wdl, dgl, hdl, ip, op, out);
}

// Round 4
// 579.549 us; speedup vs baseline: 18.6163x; 1.4737x over previous
//
#include <hip/hip_runtime.h>
#include <math.h>

namespace {

typedef __attribute__((ext_vector_type(8))) short bf16x8;
typedef __attribute__((ext_vector_type(4))) float f32x4;

constexpr int NCg = 128;

// ---- scalar helpers ----
__device__ inline short bfr(float f) {            // fp32 -> bf16 RNE
    unsigned u = __float_as_uint(f);
    unsigned r = (u + 0x7fffu + ((u >> 16) & 1u)) >> 16;
    return (short)r;
}
__device__ inline float bf2f(short s) {
    return __uint_as_float(((unsigned)(unsigned short)s) << 16);
}
__device__ inline unsigned pack2(float a, float b) {
    return (unsigned)(unsigned short)bfr(a) | ((unsigned)(unsigned short)bfr(b) << 16);
}
__device__ inline float tanh_f(float x) {         // 1 - 2/(e^{2x}+1)
    float t = __builtin_amdgcn_exp2f(x * 2.8853900817779268f);
    return 1.0f - 2.0f * __builtin_amdgcn_rcpf(t + 1.0f);
}
__device__ inline float sig05(float x) { return 0.5f / (1.0f + expf(-x)); }

// ---- swizzled LDS accessors (byte ^= (row&7)<<4) ----
__device__ inline float* hptr(float* base, int i, int d) {          // fp32 [64][64]
    int byte = (i << 8) + (d << 2); byte ^= (i & 7) << 4;
    return (float*)((char*)base + byte);
}
__device__ inline bf16x8 ld64(const short* base, int row, int kbyte) {   // bf16 pitch 64
    int byte = (row << 7) + kbyte; byte ^= (row & 7) << 4;
    return *(const bf16x8*)((const char*)base + byte);
}
__device__ inline bf16x8 ld128(const short* base, int row, int kbyte) {  // bf16 pitch 128
    int byte = (row << 8) + kbyte; byte ^= (row & 7) << 4;
    return *(const bf16x8*)((const char*)base + byte);
}
__device__ inline short* p16_64(short* base, int row, int col) {
    int byte = (row << 7) + (col << 1); byte ^= (row & 7) << 4;
    return (short*)((char*)base + byte);
}
__device__ inline void st32_64(short* base, int row, int col, unsigned v) { // col even
    int byte = (row << 7) + (col << 1); byte ^= (row & 7) << 4;
    *(unsigned*)((char*)base + byte) = v;
}
__device__ inline void st32_128(short* base, int row, int col, unsigned v) { // col even
    int byte = (row << 8) + (col << 1); byte ^= (row & 7) << 4;
    *(unsigned*)((char*)base + byte) = v;
}
__device__ inline bf16x8 ldg_bf(const float* p) {  // 8 fp32 -> bf16x8 (prologue only)
    float4 a = *(const float4*)p, b = *(const float4*)(p + 4);
    bf16x8 r;
    r[0]=bfr(a.x); r[1]=bfr(a.y); r[2]=bfr(a.z); r[3]=bfr(a.w);
    r[4]=bfr(b.x); r[5]=bfr(b.y); r[6]=bfr(b.z); r[7]=bfr(b.w);
    return r;
}
#define MFMA(a,b,c) __builtin_amdgcn_mfma_f32_16x16x32_bf16(a, b, c, 0, 0, 0)

// init: w2 fp32 [64][128] -> bf16 in ws
__global__ void cvt_w2(const float* __restrict__ w2, short* __restrict__ w2b) {
    int e = blockIdx.x * 256 + threadIdx.x;   // 8192 elems
    w2b[e] = bfr(w2[e]);
}

__global__ __launch_bounds__(256, 4) void memgraph_mfma(
    const float* __restrict__ x,      const float* __restrict__ h0,
    const float* __restrict__ W0,     const float* __restrict__ heb0,
    const float* __restrict__ nid,    const float* __restrict__ w1,
    const float* __restrict__ b1,     const short* __restrict__ w2b,
    const float* __restrict__ b2,     const float* __restrict__ injw,
    const float* __restrict__ injb,   const float* __restrict__ wdl,
    const float* __restrict__ dgl,    const float* __restrict__ hdl,
    const int*  __restrict__ iport,   const int*  __restrict__ oport,
    float* __restrict__ out)
{
    __shared__ float h_s[64 * 64];                                   // 16384 B
    __shared__ short heb_s[64 * 64];                                 //  8192 B
    __shared__ short arena[8192] __attribute__((aligned(16)));       // 16384 B
    // total 40960 B -> exactly 4 blocks/CU

    short* m1A  = arena;              // S0: m1 [i][k]      (post-P2)
    short* hinT = arena + 4096;       // S1: h_in^T [d][j]  (persistent across step)
    short* hidA = arena;              // S0+S1: hid [i][hh] pitch 128 (post-P3a)
    short* hnA  = arena;              // S0: h_new [i][d]   (post-P5)

    const int bc  = blockIdx.x;
    const int b   = bc >> 7;
    const int c   = bc & (NCg - 1);
    const int tid = threadIdx.x;
    const int Wv  = tid >> 6;          // wave 0..3
    const int l   = tid & 63;
    const int g   = l >> 4;
    const int lm  = l & 15;
    const int rowC = 16 * Wv + 4 * g;  // C-frag row base (+reg r)
    const int rowA = 16 * Wv + lm;     // A-frag row
    const int kb0  = 16 * g;           // fragment k-byte base

    const size_t cellBase = (size_t)bc;

    // ---- stage state ----
    const float* h0p  = h0   + cellBase * 4096;
    const float* hb0p = heb0 + cellBase * 4096;
    #pragma unroll
    for (int u = 0; u < 16; ++u) {
        int e = tid + 256 * u;
        *hptr(h_s, e >> 6, e & 63)     = h0p[e];
        *p16_64(heb_s, e >> 6, e & 63) = bfr(hb0p[e]);
    }

    // ---- hoisted per-lane constants ----
    float gi4[4], hg4[4], nbv[16], b1v8[8], w0a[16];
    #pragma unroll
    for (int r = 0; r < 4; ++r) {
        gi4[r] = sig05(dgl[c * 64 + rowC + r]);
        hg4[r] = sig05(hdl[c * 64 + rowC + r]);
    }
    float wdecA = 1.0f - sig05(wdl[c * 64 + rowA]);
    float wpowA = 1.0f;
    #pragma unroll
    for (int nt = 0; nt < 4; ++nt)
        #pragma unroll
        for (int r = 0; r < 4; ++r)
            nbv[nt * 4 + r] = b2[lm + 16 * nt] +
                nid[((size_t)c * 64 + rowC + r) * 64 + lm + 16 * nt];
    #pragma unroll
    for (int mt = 0; mt < 2; ++mt)
        #pragma unroll
        for (int r = 0; r < 4; ++r)
            b1v8[mt * 4 + r] = b1[32 * Wv + 16 * mt + 4 * g + r];
    {   // W0 A-layout slice: W0[rowA][8g+jj] and [32+8g+jj]
        const float* w0row = W0 + cellBase * 4096 + (size_t)rowA * 64;
        #pragma unroll
        for (int jj = 0; jj < 8; ++jj) {
            w0a[jj]     = w0row[8 * g + jj];
            w0a[8 + jj] = w0row[32 + 8 * g + jj];
        }
    }
    bf16x8 aw[2][2];   // w1 fragments, converted once
    #pragma unroll
    for (int mt = 0; mt < 2; ++mt)
        #pragma unroll
        for (int kt = 0; kt < 2; ++kt)
            aw[mt][kt] = ldg_bf(w1 + (32 * Wv + 16 * mt + lm) * 64 + 8 * g + 32 * kt);

    const int dn  = tid & 63;
    const int pin = iport[c * 4 + Wv];
    int op4[4];
    #pragma unroll
    for (int a = 0; a < 4; ++a) op4[a] = oport[c * 4 + a];
    const float* injrow  = injw + ((size_t)c * 256 + tid) * 64;
    const float  injbias = injb[c * 256 + tid];

    __syncthreads();

    // ---- prologue: hinT = h^T (bf16) ----
    {
        int d = tid >> 2, q = tid & 3;
        #pragma unroll
        for (int k = 0; k < 16; k += 2) {
            int col = 16 * q + k;
            st32_64(hinT, d, col, pack2(*hptr(h_s, col, d), *hptr(h_s, col + 1, d)));
        }
    }
    __syncthreads();

    const f32x4 zf = {0.f, 0.f, 0.f, 0.f};

    #pragma unroll 1
    for (int t = 0; t < 16; ++t) {
        int go = 0; asm volatile("" : "+v"(go));   // block LICM of t-invariant loads

        // ==== P1a: injection + scatter ====
        const float4* xt = (const float4*)(x + (((size_t)b * 16 + t) * NCg + c) * 64);
        float inj = injbias;
        #pragma unroll 4
        for (int k = 0; k < 16; ++k) {
            float4 wv = *(const float4*)(injrow + 4 * k + go);
            float4 xv = xt[k];
            inj += wv.x * xv.x + wv.y * xv.y + wv.z * xv.z + wv.w * xv.w;
        }
        atomicAdd(hptr(h_s, pin, dn), inj);
        __syncthreads();                                           // B1
        // ==== P1b: patch scattered columns of hinT ====
        *p16_64(hinT, dn, pin) = bfr(*hptr(h_s, pin, dn));
        __syncthreads();                                           // B2

        // ==== P2: m1 = (wpow*W0 + heb) @ h_in ; A built on the fly ====
        f32x4 acc2[4] = {zf, zf, zf, zf};
        {
            bf16x8 hb0 = ld64(heb_s, rowA, kb0);
            bf16x8 hb1 = ld64(heb_s, rowA, kb0 + 64);
            bf16x8 a0, a1;
            #pragma unroll
            for (int jj = 0; jj < 8; ++jj) {
                a0[jj] = bfr(fmaf(wpowA, w0a[jj],     bf2f(hb0[jj])));
                a1[jj] = bfr(fmaf(wpowA, w0a[8 + jj], bf2f(hb1[jj])));
            }
            #pragma unroll
            for (int nt = 0; nt < 4; ++nt) {
                bf16x8 bb0 = ld64(hinT, lm + 16 * nt, kb0);
                bf16x8 bb1 = ld64(hinT, lm + 16 * nt, kb0 + 64);
                acc2[nt] = MFMA(a0, bb0, acc2[nt]);
                acc2[nt] = MFMA(a1, bb1, acc2[nt]);
            }
        }
        // write m1A (S0) — no alias with hinT(S1)/heb_s, no barrier needed first
        #pragma unroll
        for (int nt = 0; nt < 4; ++nt)
            #pragma unroll
            for (int r = 0; r < 4; ++r)
                *p16_64(m1A, rowC + r, lm + 16 * nt) = bfr(acc2[nt][r]);
        __syncthreads();                                           // B4 (m1 handoff)

        // ==== P3a: hidT = w1 @ m1^T (then +b1, tanh) ====
        f32x4 acc3[2][4] = {{zf, zf, zf, zf}, {zf, zf, zf, zf}};
        #pragma unroll
        for (int kt = 0; kt < 2; ++kt)
            #pragma unroll
            for (int nt = 0; nt < 4; ++nt) {
                bf16x8 bb = ld64(m1A, lm + 16 * nt, kb0 + 64 * kt);
                acc3[0][nt] = MFMA(aw[0][kt], bb, acc3[0][nt]);
                acc3[1][nt] = MFMA(aw[1][kt], bb, acc3[1][nt]);
            }
        __syncthreads();                                           // B5 (m1A dead)
        #pragma unroll
        for (int mt = 0; mt < 2; ++mt)
            #pragma unroll
            for (int nt = 0; nt < 4; ++nt)
                #pragma unroll
                for (int rp = 0; rp < 4; rp += 2) {
                    float v0 = tanh_f(acc3[mt][nt][rp]     + b1v8[mt * 4 + rp]);
                    float v1 = tanh_f(acc3[mt][nt][rp + 1] + b1v8[mt * 4 + rp + 1]);
                    st32_128(hidA, lm + 16 * nt, 32 * Wv + 16 * mt + 4 * g + rp, pack2(v0, v1));
                }
        __syncthreads();                                           // B6 (hid handoff)

        // ==== P3b: m2 = hid @ w2^T  (w2 pre-converted bf16 in ws) ====
        f32x4 accB[4] = {zf, zf, zf, zf};
        {
            bf16x8 ah[4];
            #pragma unroll
            for (int kt = 0; kt < 4; ++kt)
                ah[kt] = ld128(hidA, 16 * Wv + lm, kb0 + 64 * kt);
            #pragma unroll
            for (int kt = 0; kt < 4; ++kt)
                #pragma unroll
                for (int nt = 0; nt < 4; ++nt) {
                    const short* w2r = w2b + ((lm + 16 * nt) << 7) + 8 * g + 32 * kt + go;
                    bf16x8 bb = *(const bf16x8*)w2r;
                    accB[nt] = MFMA(ah[kt], bb, accB[nt]);
                }
        }
        __syncthreads();                                           // B7 (hidA dead)

        // ==== P5: gated state update; write h_s, hnA, hinT(next) ====
        #pragma unroll
        for (int nt = 0; nt < 4; ++nt) {
            int d = lm + 16 * nt;
            float hv[4];
            #pragma unroll
            for (int r = 0; r < 4; ++r) {
                int i = rowC + r;
                float hin = *hptr(h_s, i, d);
                float tv  = tanh_f(accB[nt][r] + nbv[nt * 4 + r]);
                hv[r] = (1.0f - gi4[r]) * hin + gi4[r] * tv;
                *hptr(h_s, i, d) = hv[r];
                *p16_64(hnA, i, d) = bfr(hv[r]);
            }
            st32_64(hinT, d, rowC,     pack2(hv[0], hv[1]));
            st32_64(hinT, d, rowC + 2, pack2(hv[2], hv[3]));
        }
        __syncthreads();                                           // B8 (h_new handoff)

        // ==== P6: hebbian outer product + readout ====
        f32x4 acc6[4] = {zf, zf, zf, zf};
        {
            bf16x8 ha0 = ld64(hnA, rowA, kb0);
            bf16x8 ha1 = ld64(hnA, rowA, kb0 + 64);
            #pragma unroll
            for (int nt = 0; nt < 4; ++nt) {
                bf16x8 bb0 = ld64(hnA, lm + 16 * nt, kb0);
                bf16x8 bb1 = ld64(hnA, lm + 16 * nt, kb0 + 64);
                acc6[nt] = MFMA(ha0, bb0, acc6[nt]);
                acc6[nt] = MFMA(ha1, bb1, acc6[nt]);
            }
        }
        if (tid < 64) {   // readout of h_new (stable during P6)
            float ro = 0.125f * (*hptr(h_s, op4[0], tid) + *hptr(h_s, op4[1], tid) +
                                 *hptr(h_s, op4[2], tid) + *hptr(h_s, op4[3], tid));
            out[(((size_t)b * 16 + t) * NCg + c) * 64 + tid] = ro;
        }
        #pragma unroll
        for (int nt = 0; nt < 4; ++nt)
            #pragma unroll
            for (int r = 0; r < 4; ++r) {
                int i = rowC + r, j = lm + 16 * nt;
                short* hb = p16_64(heb_s, i, j);
                float nv = (1.0f - hg4[r]) * bf2f(*hb) + hg4[r] * (acc6[nt][r] * 0.015625f);
                *hb = (j == i) ? (short)0 : bfr(nv);
            }
        wpowA *= wdecA;
        __syncthreads();                                           // B9 (protect h_s/heb)
    }
}

} // namespace

extern "C" void kernel_launch(void* const* d_in, const int* in_sizes, int n_in,
                              void* d_out, int out_size, void* d_ws, size_t ws_size,
                              hipStream_t stream) {
    (void)in_sizes; (void)n_in; (void)out_size; (void)ws_size;
    const float* x    = (const float*)d_in[0];
    const float* h0   = (const float*)d_in[1];
    const float* W0   = (const float*)d_in[2];
    const float* heb0 = (const float*)d_in[3];
    const float* nid  = (const float*)d_in[4];
    const float* w1   = (const float*)d_in[5];
    const float* b1   = (const float*)d_in[6];
    const float* w2   = (const float*)d_in[7];
    const float* b2   = (const float*)d_in[8];
    const float* injw = (const float*)d_in[9];
    const float* injb = (const float*)d_in[10];
    const float* wdl  = (const float*)d_in[11];
    const float* dgl  = (const float*)d_in[12];
    const float* hdl  = (const float*)d_in[13];
    const int*   ip   = (const int*)d_in[14];
    const int*   op   = (const int*)d_in[15];
    float* out = (float*)d_out;

    short* w2b = (short*)d_ws;                       // 16 KB scratch
    cvt_w2<<<dim3(32), dim3(256), 0, stream>>>(w2, w2b);
    memgraph_mfma<<<dim3(8 * NCg), dim3(256), 0, stream>>>(
        x, h0, W0, heb0, nid, w1, b1, w2b, b2, injw, injb,
        wdl, dgl, hdl, ip, op, out);
}

// Round 5
// 559.842 us; speedup vs baseline: 19.2717x; 1.0352x over previous
//
#include <hip/hip_runtime.h>
#include <math.h>

namespace {

typedef __attribute__((ext_vector_type(8))) short bf16x8;
typedef __attribute__((ext_vector_type(4))) float f32x4;

constexpr int NCg = 128;

// ---- scalar helpers ----
__device__ inline short bfr(float f) {            // fp32 -> bf16 RNE
    unsigned u = __float_as_uint(f);
    unsigned r = (u + 0x7fffu + ((u >> 16) & 1u)) >> 16;
    return (short)r;
}
__device__ inline float bf2f(short s) {
    return __uint_as_float(((unsigned)(unsigned short)s) << 16);
}
__device__ inline unsigned pack2(float a, float b) {
    return (unsigned)(unsigned short)bfr(a) | ((unsigned)(unsigned short)bfr(b) << 16);
}
__device__ inline float tanh_f(float x) {         // 1 - 2/(e^{2x}+1)
    float t = __builtin_amdgcn_exp2f(x * 2.8853900817779268f);
    return 1.0f - 2.0f * __builtin_amdgcn_rcpf(t + 1.0f);
}
__device__ inline float sig05(float x) { return 0.5f / (1.0f + expf(-x)); }

// ---- swizzled LDS accessors (byte ^= (row&7)<<4) ----
__device__ inline float* hptr(float* base, int i, int d) {          // fp32 [64][64]
    int byte = (i << 8) + (d << 2); byte ^= (i & 7) << 4;
    return (float*)((char*)base + byte);
}
__device__ inline bf16x8 ld64(const short* base, int row, int kbyte) {   // bf16 pitch 64
    int byte = (row << 7) + kbyte; byte ^= (row & 7) << 4;
    return *(const bf16x8*)((const char*)base + byte);
}
__device__ inline bf16x8 ld128(const short* base, int row, int kbyte) {  // bf16 pitch 128
    int byte = (row << 8) + kbyte; byte ^= (row & 7) << 4;
    return *(const bf16x8*)((const char*)base + byte);
}
__device__ inline short* p16_64(short* base, int row, int col) {
    int byte = (row << 7) + (col << 1); byte ^= (row & 7) << 4;
    return (short*)((char*)base + byte);
}
__device__ inline void st32_64(short* base, int row, int col, unsigned v) { // col even
    int byte = (row << 7) + (col << 1); byte ^= (row & 7) << 4;
    *(unsigned*)((char*)base + byte) = v;
}
__device__ inline void st32_128(short* base, int row, int col, unsigned v) { // col even
    int byte = (row << 8) + (col << 1); byte ^= (row & 7) << 4;
    *(unsigned*)((char*)base + byte) = v;
}
__device__ inline bf16x8 ldg_bf(const float* p) {  // 8 fp32 -> bf16x8 (prologue only)
    float4 a = *(const float4*)p, b = *(const float4*)(p + 4);
    bf16x8 r;
    r[0]=bfr(a.x); r[1]=bfr(a.y); r[2]=bfr(a.z); r[3]=bfr(a.w);
    r[4]=bfr(b.x); r[5]=bfr(b.y); r[6]=bfr(b.z); r[7]=bfr(b.w);
    return r;
}
#define MFMA(a,b,c) __builtin_amdgcn_mfma_f32_16x16x32_bf16(a, b, c, 0, 0, 0)

// init: w2 fp32 [64][128] -> bf16 in ws
__global__ void cvt_w2(const float* __restrict__ w2, short* __restrict__ w2b) {
    int e = blockIdx.x * 256 + threadIdx.x;   // 8192 elems
    w2b[e] = bfr(w2[e]);
}

// init: inj[bt,c,p] = injb[c,p] + x[bt,c,:] . injw[c,p,:]   (exact fp32)
__global__ __launch_bounds__(256) void inj_gemm(
    const float* __restrict__ x,     // [128 bt][128 c][64]
    const float* __restrict__ injw,  // [c][256][64]
    const float* __restrict__ injb,  // [c][256]
    float* __restrict__ inj)         // [bt][c][256]
{
    const int c = blockIdx.x;        // 128
    const int p = threadIdx.x;       // 256
    float w[64];
    const float* wr = injw + ((size_t)c * 256 + p) * 64;
    #pragma unroll
    for (int k = 0; k < 64; k += 4) {
        float4 v = *(const float4*)(wr + k);
        w[k] = v.x; w[k+1] = v.y; w[k+2] = v.z; w[k+3] = v.w;
    }
    const float bias = injb[c * 256 + p];
    __shared__ float xs[16][64];
    #pragma unroll 1
    for (int chunk = 0; chunk < 8; ++chunk) {
        const int bt0 = chunk * 16;
        {   // stage 16 bt-rows of x for this c
            int e = threadIdx.x * 4;
            *(float4*)&xs[e >> 6][e & 63] =
                *(const float4*)(x + ((size_t)(bt0 + (e >> 6)) * NCg + c) * 64 + (e & 63));
        }
        __syncthreads();
        #pragma unroll 1
        for (int r = 0; r < 16; ++r) {
            float acc = bias;
            #pragma unroll
            for (int k = 0; k < 64; ++k) acc = fmaf(w[k], xs[r][k], acc);
            inj[((size_t)(bt0 + r) * NCg + c) * 256 + p] = acc;
        }
        __syncthreads();
    }
}

__global__ __launch_bounds__(256, 4) void memgraph_mfma(
    const float* __restrict__ inj,    const float* __restrict__ h0,
    const float* __restrict__ W0,     const float* __restrict__ heb0,
    const float* __restrict__ nid,    const float* __restrict__ w1,
    const float* __restrict__ b1,     const short* __restrict__ w2b,
    const float* __restrict__ b2,     const float* __restrict__ wdl,
    const float* __restrict__ dgl,    const float* __restrict__ hdl,
    const int*  __restrict__ iport,   const int*  __restrict__ oport,
    float* __restrict__ out)
{
    __shared__ float h_s[64 * 64];                                   // 16384 B
    __shared__ short heb_s[64 * 64];                                 //  8192 B
    __shared__ short arena[8192] __attribute__((aligned(16)));       // 16384 B
    // total 40960 B -> exactly 4 blocks/CU

    short* m1A  = arena;              // S0: m1 [i][k]      (post-P2)
    short* hinT = arena + 4096;       // S1: h_in^T [d][j]  (rebuilt each step in P5)
    short* hidA = arena;              // S0+S1: hid [i][hh] pitch 128 (post-P3a)
    short* hnA  = arena;              // S0: h_new [i][d]   (post-P5)

    const int bc  = blockIdx.x;
    const int b   = bc >> 7;
    const int c   = bc & (NCg - 1);
    const int tid = threadIdx.x;
    const int Wv  = tid >> 6;          // wave 0..3
    const int l   = tid & 63;
    const int g   = l >> 4;
    const int lm  = l & 15;
    const int rowC = 16 * Wv + 4 * g;  // C-frag row base (+reg r)
    const int rowA = 16 * Wv + lm;     // A-frag row
    const int kb0  = 16 * g;           // fragment k-byte base

    const size_t cellBase = (size_t)bc;

    // ---- stage state ----
    const float* h0p  = h0   + cellBase * 4096;
    const float* hb0p = heb0 + cellBase * 4096;
    #pragma unroll
    for (int u = 0; u < 16; ++u) {
        int e = tid + 256 * u;
        *hptr(h_s, e >> 6, e & 63)     = h0p[e];
        *p16_64(heb_s, e >> 6, e & 63) = bfr(hb0p[e]);
    }

    // ---- hoisted per-lane constants ----
    float gi4[4], hg4[4], nbv[16], b1v8[8], w0a[16];
    #pragma unroll
    for (int r = 0; r < 4; ++r) {
        gi4[r] = sig05(dgl[c * 64 + rowC + r]);
        hg4[r] = sig05(hdl[c * 64 + rowC + r]);
    }
    float wdecA = 1.0f - sig05(wdl[c * 64 + rowA]);
    float wpowA = 1.0f;
    #pragma unroll
    for (int nt = 0; nt < 4; ++nt)
        #pragma unroll
        for (int r = 0; r < 4; ++r)
            nbv[nt * 4 + r] = b2[lm + 16 * nt] +
                nid[((size_t)c * 64 + rowC + r) * 64 + lm + 16 * nt];
    #pragma unroll
    for (int mt = 0; mt < 2; ++mt)
        #pragma unroll
        for (int r = 0; r < 4; ++r)
            b1v8[mt * 4 + r] = b1[32 * Wv + 16 * mt + 4 * g + r];
    {   // W0 A-layout slice
        const float* w0row = W0 + cellBase * 4096 + (size_t)rowA * 64;
        #pragma unroll
        for (int jj = 0; jj < 8; ++jj) {
            w0a[jj]     = w0row[8 * g + jj];
            w0a[8 + jj] = w0row[32 + 8 * g + jj];
        }
    }
    bf16x8 aw[2][2];   // w1 fragments, converted once
    #pragma unroll
    for (int mt = 0; mt < 2; ++mt)
        #pragma unroll
        for (int kt = 0; kt < 2; ++kt)
            aw[mt][kt] = ldg_bf(w1 + (32 * Wv + 16 * mt + lm) * 64 + 8 * g + 32 * kt);
    bf16x8 w2f[8];     // w2 fragments kt=0,1 hoisted (kt=2,3 loaded per step)
    #pragma unroll
    for (int nt = 0; nt < 4; ++nt)
        #pragma unroll
        for (int kt = 0; kt < 2; ++kt)
            w2f[nt * 2 + kt] = *(const bf16x8*)(w2b + ((lm + 16 * nt) << 7) + 8 * g + 32 * kt);

    const int dn = l;
    int ip4[4], op4[4];
    #pragma unroll
    for (int a = 0; a < 4; ++a) { ip4[a] = iport[c * 4 + a]; op4[a] = oport[c * 4 + a]; }
    const int pin = ip4[Wv];
    const bool own = !((Wv > 0 && ip4[0] == pin) ||
                       (Wv > 1 && ip4[1] == pin) ||
                       (Wv > 2 && ip4[2] == pin));

    // inj prefetch for t=0
    float injv[4];
    {
        const float* ir = inj + (((size_t)b * 16) * NCg + c) * 256 + dn;
        #pragma unroll
        for (int a = 0; a < 4; ++a) injv[a] = ir[a * 64];
    }

    __syncthreads();

    // ---- prologue: hinT = h^T (bf16) ----
    {
        int d = tid >> 2, q = tid & 3;
        #pragma unroll
        for (int k = 0; k < 16; k += 2) {
            int col = 16 * q + k;
            st32_64(hinT, d, col, pack2(*hptr(h_s, col, d), *hptr(h_s, col + 1, d)));
        }
    }
    __syncthreads();

    const f32x4 zf = {0.f, 0.f, 0.f, 0.f};

    #pragma unroll 1
    for (int t = 0; t < 16; ++t) {
        int go = 0; asm volatile("" : "+v"(go));   // block LICM of t-invariant loads

        // ==== P1: scatter (owner wave per distinct port; plain stores) ====
        if (own) {
            float v = 0.0f;
            #pragma unroll
            for (int a = 0; a < 4; ++a)
                if (ip4[a] == pin) v += injv[a];     // wave-uniform branch
            float hv = *hptr(h_s, pin, dn) + v;
            *hptr(h_s, pin, dn) = hv;
            *p16_64(hinT, dn, pin) = bfr(hv);
        }
        __syncthreads();                                           // B1

        // ==== P2: m1 = (wpow*W0 + heb) @ h_in ; A built on the fly ====
        f32x4 acc2[4] = {zf, zf, zf, zf};
        {
            bf16x8 hb0 = ld64(heb_s, rowA, kb0);
            bf16x8 hb1 = ld64(heb_s, rowA, kb0 + 64);
            bf16x8 a0, a1;
            #pragma unroll
            for (int jj = 0; jj < 8; ++jj) {
                a0[jj] = bfr(fmaf(wpowA, w0a[jj],     bf2f(hb0[jj])));
                a1[jj] = bfr(fmaf(wpowA, w0a[8 + jj], bf2f(hb1[jj])));
            }
            #pragma unroll
            for (int nt = 0; nt < 4; ++nt) {
                bf16x8 bb0 = ld64(hinT, lm + 16 * nt, kb0);
                bf16x8 bb1 = ld64(hinT, lm + 16 * nt, kb0 + 64);
                acc2[nt] = MFMA(a0, bb0, acc2[nt]);
                acc2[nt] = MFMA(a1, bb1, acc2[nt]);
            }
        }
        // write m1A (S0) — disjoint from hinT(S1)/heb_s
        #pragma unroll
        for (int nt = 0; nt < 4; ++nt)
            #pragma unroll
            for (int r = 0; r < 4; ++r)
                *p16_64(m1A, rowC + r, lm + 16 * nt) = bfr(acc2[nt][r]);
        __syncthreads();                                           // B4 (m1 handoff)

        // prefetch inj for next step (used at next P1, after B9)
        {
            int tn = (t < 15) ? t + 1 : 15;
            const float* ir = inj + (((size_t)(b * 16 + tn)) * NCg + c) * 256 + dn;
            #pragma unroll
            for (int a = 0; a < 4; ++a) injv[a] = ir[a * 64];
        }

        // ==== P3a: hidT = w1 @ m1^T (then +b1, tanh) ====
        f32x4 acc3[2][4] = {{zf, zf, zf, zf}, {zf, zf, zf, zf}};
        #pragma unroll
        for (int kt = 0; kt < 2; ++kt)
            #pragma unroll
            for (int nt = 0; nt < 4; ++nt) {
                bf16x8 bb = ld64(m1A, lm + 16 * nt, kb0 + 64 * kt);
                acc3[0][nt] = MFMA(aw[0][kt], bb, acc3[0][nt]);
                acc3[1][nt] = MFMA(aw[1][kt], bb, acc3[1][nt]);
            }
        __syncthreads();                                           // B5 (m1A dead)
        #pragma unroll
        for (int mt = 0; mt < 2; ++mt)
            #pragma unroll
            for (int nt = 0; nt < 4; ++nt)
                #pragma unroll
                for (int rp = 0; rp < 4; rp += 2) {
                    float v0 = tanh_f(acc3[mt][nt][rp]     + b1v8[mt * 4 + rp]);
                    float v1 = tanh_f(acc3[mt][nt][rp + 1] + b1v8[mt * 4 + rp + 1]);
                    st32_128(hidA, lm + 16 * nt, 32 * Wv + 16 * mt + 4 * g + rp, pack2(v0, v1));
                }
        __syncthreads();                                           // B6 (hid handoff)

        // ==== P3b: m2 = hid @ w2^T ====
        f32x4 accB[4] = {zf, zf, zf, zf};
        {
            bf16x8 ah[4];
            #pragma unroll
            for (int kt = 0; kt < 4; ++kt)
                ah[kt] = ld128(hidA, 16 * Wv + lm, kb0 + 64 * kt);
            #pragma unroll
            for (int nt = 0; nt < 4; ++nt) {
                accB[nt] = MFMA(ah[0], w2f[nt * 2 + 0], accB[nt]);
                accB[nt] = MFMA(ah[1], w2f[nt * 2 + 1], accB[nt]);
            }
            #pragma unroll
            for (int kt = 2; kt < 4; ++kt)
                #pragma unroll
                for (int nt = 0; nt < 4; ++nt) {
                    const short* w2r = w2b + ((lm + 16 * nt) << 7) + 8 * g + 32 * kt + go;
                    bf16x8 bb = *(const bf16x8*)w2r;
                    accB[nt] = MFMA(ah[kt], bb, accB[nt]);
                }
        }
        __syncthreads();                                           // B7 (hidA dead)

        // ==== P5: gated state update; write h_s, hnA, hinT(next) ====
        #pragma unroll
        for (int nt = 0; nt < 4; ++nt) {
            int d = lm + 16 * nt;
            float hv[4];
            #pragma unroll
            for (int r = 0; r < 4; ++r) {
                int i = rowC + r;
                float hin = *hptr(h_s, i, d);
                float tv  = tanh_f(accB[nt][r] + nbv[nt * 4 + r]);
                hv[r] = (1.0f - gi4[r]) * hin + gi4[r] * tv;
                *hptr(h_s, i, d) = hv[r];
                *p16_64(hnA, i, d) = bfr(hv[r]);
            }
            st32_64(hinT, d, rowC,     pack2(hv[0], hv[1]));
            st32_64(hinT, d, rowC + 2, pack2(hv[2], hv[3]));
        }
        __syncthreads();                                           // B8 (h_new handoff)

        // ==== P6: hebbian outer product + readout ====
        f32x4 acc6[4] = {zf, zf, zf, zf};
        {
            bf16x8 ha0 = ld64(hnA, rowA, kb0);
            bf16x8 ha1 = ld64(hnA, rowA, kb0 + 64);
            #pragma unroll
            for (int nt = 0; nt < 4; ++nt) {
                bf16x8 bb0 = ld64(hnA, lm + 16 * nt, kb0);
                bf16x8 bb1 = ld64(hnA, lm + 16 * nt, kb0 + 64);
                acc6[nt] = MFMA(ha0, bb0, acc6[nt]);
                acc6[nt] = MFMA(ha1, bb1, acc6[nt]);
            }
        }
        if (tid < 64) {   // readout of h_new (stable during P6)
            float ro = 0.125f * (*hptr(h_s, op4[0], tid) + *hptr(h_s, op4[1], tid) +
                                 *hptr(h_s, op4[2], tid) + *hptr(h_s, op4[3], tid));
            out[(((size_t)b * 16 + t) * NCg + c) * 64 + tid] = ro;
        }
        #pragma unroll
        for (int nt = 0; nt < 4; ++nt)
            #pragma unroll
            for (int r = 0; r < 4; ++r) {
                int i = rowC + r, j = lm + 16 * nt;
                short* hb = p16_64(heb_s, i, j);
                float nv = (1.0f - hg4[r]) * bf2f(*hb) + hg4[r] * (acc6[nt][r] * 0.015625f);
                *hb = (j == i) ? (short)0 : bfr(nv);
            }
        wpowA *= wdecA;
        __syncthreads();                                           // B9 (protect h_s/heb/hinT)
    }
}

} // namespace

extern "C" void kernel_launch(void* const* d_in, const int* in_sizes, int n_in,
                              void* d_out, int out_size, void* d_ws, size_t ws_size,
                              hipStream_t stream) {
    (void)in_sizes; (void)n_in; (void)out_size; (void)ws_size;
    const float* x    = (const float*)d_in[0];
    const float* h0   = (const float*)d_in[1];
    const float* W0   = (const float*)d_in[2];
    const float* heb0 = (const float*)d_in[3];
    const float* nid  = (const float*)d_in[4];
    const float* w1   = (const float*)d_in[5];
    const float* b1   = (const float*)d_in[6];
    const float* w2   = (const float*)d_in[7];
    const float* b2   = (const float*)d_in[8];
    const float* injw = (const float*)d_in[9];
    const float* injb = (const float*)d_in[10];
    const float* wdl  = (const float*)d_in[11];
    const float* dgl  = (const float*)d_in[12];
    const float* hdl  = (const float*)d_in[13];
    const int*   ip   = (const int*)d_in[14];
    const int*   op   = (const int*)d_in[15];
    float* out = (float*)d_out;

    short* w2b = (short*)d_ws;                         // 16 KB
    float* inj = (float*)((char*)d_ws + 32768);        // 16 MB fp32 [bt][c][256]

    cvt_w2<<<dim3(32), dim3(256), 0, stream>>>(w2, w2b);
    inj_gemm<<<dim3(128), dim3(256), 0, stream>>>(x, injw, injb, inj);
    memgraph_mfma<<<dim3(8 * NCg), dim3(256), 0, stream>>>(
        inj, h0, W0, heb0, nid, w1, b1, w2b, b2,
        wdl, dgl, hdl, ip, op, out);
}

// Round 6
// 554.779 us; speedup vs baseline: 19.4475x; 1.0091x over previous
//
#include <hip/hip_runtime.h>
#include <math.h>

namespace {

typedef __attribute__((ext_vector_type(8))) short bf16x8;
typedef __attribute__((ext_vector_type(4))) float f32x4;

constexpr int NCg = 128;

// ---- scalar helpers ----
__device__ inline short bfr(float f) {            // fp32 -> bf16 RNE
    unsigned u = __float_as_uint(f);
    unsigned r = (u + 0x7fffu + ((u >> 16) & 1u)) >> 16;
    return (short)r;
}
__device__ inline float bf2f(short s) {
    return __uint_as_float(((unsigned)(unsigned short)s) << 16);
}
__device__ inline unsigned pack2(float a, float b) {
    return (unsigned)(unsigned short)bfr(a) | ((unsigned)(unsigned short)bfr(b) << 16);
}
__device__ inline float tanh_f(float x) {         // 1 - 2/(e^{2x}+1)
    float t = __builtin_amdgcn_exp2f(x * 2.8853900817779268f);
    return 1.0f - 2.0f * __builtin_amdgcn_rcpf(t + 1.0f);
}
__device__ inline float sig05(float x) { return 0.5f / (1.0f + expf(-x)); }

// ---- swizzled LDS accessors (byte ^= (row&7)<<4) ----
__device__ inline float* hptr(float* base, int i, int d) {          // fp32 [64][64]
    int byte = (i << 8) + (d << 2); byte ^= (i & 7) << 4;
    return (float*)((char*)base + byte);
}
__device__ inline bf16x8 ld64(const short* base, int row, int kbyte) {   // bf16 pitch 64
    int byte = (row << 7) + kbyte; byte ^= (row & 7) << 4;
    return *(const bf16x8*)((const char*)base + byte);
}
__device__ inline bf16x8 ld128(const short* base, int row, int kbyte) {  // bf16 pitch 128
    int byte = (row << 8) + kbyte; byte ^= (row & 7) << 4;
    return *(const bf16x8*)((const char*)base + byte);
}
__device__ inline short* p16_64(short* base, int row, int col) {
    int byte = (row << 7) + (col << 1); byte ^= (row & 7) << 4;
    return (short*)((char*)base + byte);
}
__device__ inline void st32_64(short* base, int row, int col, unsigned v) { // col even
    int byte = (row << 7) + (col << 1); byte ^= (row & 7) << 4;
    *(unsigned*)((char*)base + byte) = v;
}
__device__ inline void st32_128(short* base, int row, int col, unsigned v) { // col even
    int byte = (row << 8) + (col << 1); byte ^= (row & 7) << 4;
    *(unsigned*)((char*)base + byte) = v;
}
__device__ inline bf16x8 ldg_bf(const float* p) {  // 8 fp32 -> bf16x8 (prologue only)
    float4 a = *(const float4*)p, b = *(const float4*)(p + 4);
    bf16x8 r;
    r[0]=bfr(a.x); r[1]=bfr(a.y); r[2]=bfr(a.z); r[3]=bfr(a.w);
    r[4]=bfr(b.x); r[5]=bfr(b.y); r[6]=bfr(b.z); r[7]=bfr(b.w);
    return r;
}
#define MFMA(a,b,c) __builtin_amdgcn_mfma_f32_16x16x32_bf16(a, b, c, 0, 0, 0)
#define PIN(v) asm volatile("" : "+v"(v))

// init: w2 fp32 [64][128] -> bf16 in ws
__global__ void cvt_w2(const float* __restrict__ w2, short* __restrict__ w2b) {
    int e = blockIdx.x * 256 + threadIdx.x;   // 8192 elems
    w2b[e] = bfr(w2[e]);
}

// init: inj[bt,c,p] = injb[c,p] + x[bt,c,:] . injw[c,p,:]   (exact fp32)
__global__ __launch_bounds__(256) void inj_gemm(
    const float* __restrict__ x,     // [128 bt][128 c][64]
    const float* __restrict__ injw,  // [c][256][64]
    const float* __restrict__ injb,  // [c][256]
    float* __restrict__ inj)         // [bt][c][256]
{
    const int c = blockIdx.x;        // 128
    const int p = threadIdx.x;       // 256
    float w[64];
    const float* wr = injw + ((size_t)c * 256 + p) * 64;
    #pragma unroll
    for (int k = 0; k < 64; k += 4) {
        float4 v = *(const float4*)(wr + k);
        w[k] = v.x; w[k+1] = v.y; w[k+2] = v.z; w[k+3] = v.w;
    }
    const float bias = injb[c * 256 + p];
    __shared__ float xs[16][64];
    #pragma unroll 1
    for (int chunk = 0; chunk < 8; ++chunk) {
        const int bt0 = chunk * 16;
        {   // stage 16 bt-rows of x for this c
            int e = threadIdx.x * 4;
            *(float4*)&xs[e >> 6][e & 63] =
                *(const float4*)(x + ((size_t)(bt0 + (e >> 6)) * NCg + c) * 64 + (e & 63));
        }
        __syncthreads();
        #pragma unroll 1
        for (int r = 0; r < 16; ++r) {
            float acc = bias;
            #pragma unroll
            for (int k = 0; k < 64; ++k) acc = fmaf(w[k], xs[r][k], acc);
            inj[((size_t)(bt0 + r) * NCg + c) * 256 + p] = acc;
        }
        __syncthreads();
    }
}

__global__ __launch_bounds__(256, 4) void memgraph_mfma(
    const float* __restrict__ inj,    const float* __restrict__ h0,
    const float* __restrict__ W0,     const float* __restrict__ heb0,
    const float* __restrict__ nid,    const float* __restrict__ w1,
    const float* __restrict__ b1,     const short* __restrict__ w2b,
    const float* __restrict__ b2,     const float* __restrict__ wdl,
    const float* __restrict__ dgl,    const float* __restrict__ hdl,
    const int*  __restrict__ iport,   const int*  __restrict__ oport,
    float* __restrict__ out)
{
    __shared__ float h_s[64 * 64];                                   // 16384 B
    __shared__ short heb_s[64 * 64];                                 //  8192 B
    __shared__ short arena[8192] __attribute__((aligned(16)));       // 16384 B
    // total 40960 B -> exactly 4 blocks/CU

    short* m1A  = arena;              // S0: m1 [i][k]      (post-P2)
    short* hinT = arena + 4096;       // S1: h_in^T [d][j]  (rebuilt each step in P5)
    short* hidA = arena;              // S0+S1: hid [i][hh] pitch 128 (post-P3a)
    short* hnA  = arena;              // S0: h_new [i][d]   (post-P5)

    const int bc  = blockIdx.x;
    const int b   = bc >> 7;
    const int c   = bc & (NCg - 1);
    const int tid = threadIdx.x;
    const int Wv  = tid >> 6;          // wave 0..3
    const int l   = tid & 63;
    const int g   = l >> 4;
    const int lm  = l & 15;
    const int rowC = 16 * Wv + 4 * g;  // C-frag row base (+reg r)
    const int rowA = 16 * Wv + lm;     // A-frag row
    const int kb0  = 16 * g;           // fragment k-byte base

    const size_t cellBase = (size_t)bc;

    // ---- stage state ----
    const float* h0p  = h0   + cellBase * 4096;
    const float* hb0p = heb0 + cellBase * 4096;
    #pragma unroll
    for (int u = 0; u < 16; ++u) {
        int e = tid + 256 * u;
        *hptr(h_s, e >> 6, e & 63)     = h0p[e];
        *p16_64(heb_s, e >> 6, e & 63) = bfr(hb0p[e]);
    }

    // ---- hoisted per-lane constants (PINNED below so remat can't undo) ----
    float gi4[4], hg4[4], nbv[16], b1v8[8], w0a[16];
    #pragma unroll
    for (int r = 0; r < 4; ++r) {
        gi4[r] = sig05(dgl[c * 64 + rowC + r]);
        hg4[r] = sig05(hdl[c * 64 + rowC + r]);
    }
    float wdecA = 1.0f - sig05(wdl[c * 64 + rowA]);
    float wpowA = 1.0f;
    #pragma unroll
    for (int nt = 0; nt < 4; ++nt)
        #pragma unroll
        for (int r = 0; r < 4; ++r)
            nbv[nt * 4 + r] = b2[lm + 16 * nt] +
                nid[((size_t)c * 64 + rowC + r) * 64 + lm + 16 * nt];
    #pragma unroll
    for (int mt = 0; mt < 2; ++mt)
        #pragma unroll
        for (int r = 0; r < 4; ++r)
            b1v8[mt * 4 + r] = b1[32 * Wv + 16 * mt + 4 * g + r];
    {   // W0 A-layout slice
        const float* w0row = W0 + cellBase * 4096 + (size_t)rowA * 64;
        #pragma unroll
        for (int jj = 0; jj < 8; ++jj) {
            w0a[jj]     = w0row[8 * g + jj];
            w0a[8 + jj] = w0row[32 + 8 * g + jj];
        }
    }
    bf16x8 aw[2][2];   // w1 fragments, converted once
    #pragma unroll
    for (int mt = 0; mt < 2; ++mt)
        #pragma unroll
        for (int kt = 0; kt < 2; ++kt)
            aw[mt][kt] = ldg_bf(w1 + (32 * Wv + 16 * mt + lm) * 64 + 8 * g + 32 * kt);

    // ---- PIN all t-invariants in VGPRs (asm is the opaque producer;
    //      compiler cannot rematerialize the loads inside the t-loop) ----
    #pragma unroll
    for (int k = 0; k < 16; ++k) PIN(w0a[k]);
    #pragma unroll
    for (int k = 0; k < 16; ++k) PIN(nbv[k]);
    #pragma unroll
    for (int k = 0; k < 8; ++k)  PIN(b1v8[k]);
    #pragma unroll
    for (int k = 0; k < 4; ++k)  { PIN(gi4[k]); PIN(hg4[k]); }
    PIN(wdecA);
    #pragma unroll
    for (int mt = 0; mt < 2; ++mt)
        #pragma unroll
        for (int kt = 0; kt < 2; ++kt) PIN(aw[mt][kt]);

    const int dn = l;
    int ip4[4], op4[4];
    #pragma unroll
    for (int a = 0; a < 4; ++a) { ip4[a] = iport[c * 4 + a]; op4[a] = oport[c * 4 + a]; }
    const int pin = ip4[Wv];
    const bool own = !((Wv > 0 && ip4[0] == pin) ||
                       (Wv > 1 && ip4[1] == pin) ||
                       (Wv > 2 && ip4[2] == pin));

    // inj prefetch for t=0
    float injv[4];
    {
        const float* ir = inj + (((size_t)b * 16) * NCg + c) * 256 + dn;
        #pragma unroll
        for (int a = 0; a < 4; ++a) injv[a] = ir[a * 64];
    }

    __syncthreads();

    // ---- prologue: hinT = h^T (bf16) ----
    {
        int d = tid >> 2, q = tid & 3;
        #pragma unroll
        for (int k = 0; k < 16; k += 2) {
            int col = 16 * q + k;
            st32_64(hinT, d, col, pack2(*hptr(h_s, col, d), *hptr(h_s, col + 1, d)));
        }
    }
    __syncthreads();

    const f32x4 zf = {0.f, 0.f, 0.f, 0.f};

    #pragma unroll 1
    for (int t = 0; t < 16; ++t) {
        int go = 0; asm volatile("" : "+v"(go));   // offset launder for DESIRED per-step loads

        // ==== P1: scatter (owner wave per distinct port; plain stores) ====
        if (own) {
            float v = 0.0f;
            #pragma unroll
            for (int a = 0; a < 4; ++a)
                if (ip4[a] == pin) v += injv[a];     // wave-uniform branch
            float hv = *hptr(h_s, pin, dn) + v;
            *hptr(h_s, pin, dn) = hv;
            *p16_64(hinT, dn, pin) = bfr(hv);
        }
        __syncthreads();                                           // B1

        // ==== P2: m1 = (wpow*W0 + heb) @ h_in ; A built on the fly ====
        f32x4 acc2[4] = {zf, zf, zf, zf};
        {
            bf16x8 hb0 = ld64(heb_s, rowA, kb0);
            bf16x8 hb1 = ld64(heb_s, rowA, kb0 + 64);
            bf16x8 a0, a1;
            #pragma unroll
            for (int jj = 0; jj < 8; ++jj) {
                a0[jj] = bfr(fmaf(wpowA, w0a[jj],     bf2f(hb0[jj])));
                a1[jj] = bfr(fmaf(wpowA, w0a[8 + jj], bf2f(hb1[jj])));
            }
            #pragma unroll
            for (int nt = 0; nt < 4; ++nt) {
                bf16x8 bb0 = ld64(hinT, lm + 16 * nt, kb0);
                bf16x8 bb1 = ld64(hinT, lm + 16 * nt, kb0 + 64);
                acc2[nt] = MFMA(a0, bb0, acc2[nt]);
                acc2[nt] = MFMA(a1, bb1, acc2[nt]);
            }
        }
        // write m1A (S0) — disjoint from hinT(S1)/heb_s
        #pragma unroll
        for (int nt = 0; nt < 4; ++nt)
            #pragma unroll
            for (int r = 0; r < 4; ++r)
                *p16_64(m1A, rowC + r, lm + 16 * nt) = bfr(acc2[nt][r]);
        __syncthreads();                                           // B4 (m1 handoff)

        // prefetch inj for next step (used at next P1, after B9)
        {
            int tn = (t < 15) ? t + 1 : 15;
            const float* ir = inj + (((size_t)(b * 16 + tn)) * NCg + c) * 256 + dn;
            #pragma unroll
            for (int a = 0; a < 4; ++a) injv[a] = ir[a * 64];
        }

        // ==== P3a: hidT = w1 @ m1^T (then +b1, tanh) ====
        f32x4 acc3[2][4] = {{zf, zf, zf, zf}, {zf, zf, zf, zf}};
        #pragma unroll
        for (int kt = 0; kt < 2; ++kt)
            #pragma unroll
            for (int nt = 0; nt < 4; ++nt) {
                bf16x8 bb = ld64(m1A, lm + 16 * nt, kb0 + 64 * kt);
                acc3[0][nt] = MFMA(aw[0][kt], bb, acc3[0][nt]);
                acc3[1][nt] = MFMA(aw[1][kt], bb, acc3[1][nt]);
            }
        __syncthreads();                                           // B5 (m1A dead)
        #pragma unroll
        for (int mt = 0; mt < 2; ++mt)
            #pragma unroll
            for (int nt = 0; nt < 4; ++nt)
                #pragma unroll
                for (int rp = 0; rp < 4; rp += 2) {
                    float v0 = tanh_f(acc3[mt][nt][rp]     + b1v8[mt * 4 + rp]);
                    float v1 = tanh_f(acc3[mt][nt][rp + 1] + b1v8[mt * 4 + rp + 1]);
                    st32_128(hidA, lm + 16 * nt, 32 * Wv + 16 * mt + 4 * g + rp, pack2(v0, v1));
                }
        __syncthreads();                                           // B6 (hid handoff)

        // ==== P3b: m2 = hid @ w2^T  (w2b: 16 KB, L2-hot; per-step reload is cheap) ====
        f32x4 accB[4] = {zf, zf, zf, zf};
        {
            bf16x8 ah[4];
            #pragma unroll
            for (int kt = 0; kt < 4; ++kt)
                ah[kt] = ld128(hidA, 16 * Wv + lm, kb0 + 64 * kt);
            #pragma unroll
            for (int kt = 0; kt < 4; ++kt)
                #pragma unroll
                for (int nt = 0; nt < 4; ++nt) {
                    const short* w2r = w2b + ((lm + 16 * nt) << 7) + 8 * g + 32 * kt + go;
                    bf16x8 bb = *(const bf16x8*)w2r;
                    accB[nt] = MFMA(ah[kt], bb, accB[nt]);
                }
        }
        __syncthreads();                                           // B7 (hidA dead)

        // ==== P5: gated state update; write h_s, hnA, hinT(next) ====
        #pragma unroll
        for (int nt = 0; nt < 4; ++nt) {
            int d = lm + 16 * nt;
            float hv[4];
            #pragma unroll
            for (int r = 0; r < 4; ++r) {
                int i = rowC + r;
                float hin = *hptr(h_s, i, d);
                float tv  = tanh_f(accB[nt][r] + nbv[nt * 4 + r]);
                hv[r] = (1.0f - gi4[r]) * hin + gi4[r] * tv;
                *hptr(h_s, i, d) = hv[r];
                *p16_64(hnA, i, d) = bfr(hv[r]);
            }
            st32_64(hinT, d, rowC,     pack2(hv[0], hv[1]));
            st32_64(hinT, d, rowC + 2, pack2(hv[2], hv[3]));
        }
        __syncthreads();                                           // B8 (h_new handoff)

        // ==== P6: hebbian outer product + readout ====
        f32x4 acc6[4] = {zf, zf, zf, zf};
        {
            bf16x8 ha0 = ld64(hnA, rowA, kb0);
            bf16x8 ha1 = ld64(hnA, rowA, kb0 + 64);
            #pragma unroll
            for (int nt = 0; nt < 4; ++nt) {
                bf16x8 bb0 = ld64(hnA, lm + 16 * nt, kb0);
                bf16x8 bb1 = ld64(hnA, lm + 16 * nt, kb0 + 64);
                acc6[nt] = MFMA(ha0, bb0, acc6[nt]);
                acc6[nt] = MFMA(ha1, bb1, acc6[nt]);
            }
        }
        if (tid < 64) {   // readout of h_new (stable during P6)
            float ro = 0.125f * (*hptr(h_s, op4[0], tid) + *hptr(h_s, op4[1], tid) +
                                 *hptr(h_s, op4[2], tid) + *hptr(h_s, op4[3], tid));
            out[(((size_t)b * 16 + t) * NCg + c) * 64 + tid] = ro;
        }
        #pragma unroll
        for (int nt = 0; nt < 4; ++nt)
            #pragma unroll
            for (int r = 0; r < 4; ++r) {
                int i = rowC + r, j = lm + 16 * nt;
                short* hb = p16_64(heb_s, i, j);
                float nv = (1.0f - hg4[r]) * bf2f(*hb) + hg4[r] * (acc6[nt][r] * 0.015625f);
                *hb = (j == i) ? (short)0 : bfr(nv);
            }
        wpowA *= wdecA;
        __syncthreads();                                           // B9 (protect h_s/heb/hinT)
    }
}

} // namespace

extern "C" void kernel_launch(void* const* d_in, const int* in_sizes, int n_in,
                              void* d_out, int out_size, void* d_ws, size_t ws_size,
                              hipStream_t stream) {
    (void)in_sizes; (void)n_in; (void)out_size; (void)ws_size;
    const float* x    = (const float*)d_in[0];
    const float* h0   = (const float*)d_in[1];
    const float* W0   = (const float*)d_in[2];
    const float* heb0 = (const float*)d_in[3];
    const float* nid  = (const float*)d_in[4];
    const float* w1   = (const float*)d_in[5];
    const float* b1   = (const float*)d_in[6];
    const float* w2   = (const float*)d_in[7];
    const float* b2   = (const float*)d_in[8];
    const float* injw = (const float*)d_in[9];
    const float* injb = (const float*)d_in[10];
    const float* wdl  = (const float*)d_in[11];
    const float* dgl  = (const float*)d_in[12];
    const float* hdl  = (const float*)d_in[13];
    const int*   ip   = (const int*)d_in[14];
    const int*   op   = (const int*)d_in[15];
    float* out = (float*)d_out;

    short* w2b = (short*)d_ws;                         // 16 KB
    float* inj = (float*)((char*)d_ws + 32768);        // 16 MB fp32 [bt][c][256]

    cvt_w2<<<dim3(32), dim3(256), 0, stream>>>(w2, w2b);
    inj_gemm<<<dim3(128), dim3(256), 0, stream>>>(x, injw, injb, inj);
    memgraph_mfma<<<dim3(8 * NCg), dim3(256), 0, stream>>>(
        inj, h0, W0, heb0, nid, w1, b1, w2b, b2,
        wdl, dgl, hdl, ip, op, out);
}